// Round 10
// baseline (268.399 us; speedup 1.0000x reference)
//
#include <hip/hip_runtime.h>
#include <hip/hip_bf16.h>

// ---------------------------------------------------------------------------
// SAGEModel fused pipeline (bf16 data path, fp32 accumulation):
//   hbf  = bf16(h)                              [100000,128]
//   y0   = segsum(hbf[src0])  -> bf16           [25000,128]
//   t    = relu(y0@W1+b1)@W2  -> bf16 (MFMA)    [25000,64]
//   out  = segsum(t[src1]) + b2 -> f32          [5000,64]
//
// CSR build is SCATTER-FREE (R4-R8: any global 4B scatter ~1TB/s => >=40us):
// 236 scan blocks each own 128 dsts, scan the packed-ushort dst stream
// (L2-broadcast reads; match test = (dst>>7)==range, 2 ops), stage per-dst
// lists in LDS (33.8KB -> 4 blocks/CU so co-scheduled cast keeps occupancy),
// then flush compact lists coalesced. Overflow >64/dst -> per-range spill
// (correctness-guaranteed). No global atomics, no memsets, 5 dispatches.
// ---------------------------------------------------------------------------

#define D0_CONST 25000
#define D1_CONST 5000
#define RPB 128                 // dst rows per scan block (128-aligned ranges)
#define LCAP 64                 // per-dst list capacity
#define OVF_CAP 256             // per-range spill capacity
#define NFB0 196                // ceil(25000/128)
#define NFB1 40                 // ceil(5000/128)

typedef __attribute__((ext_vector_type(8))) short bf16x8;
typedef __attribute__((ext_vector_type(4))) float f32x4;
typedef __attribute__((ext_vector_type(4))) float f32x4v;
typedef __attribute__((ext_vector_type(4))) unsigned int u32x4;

__device__ __forceinline__ unsigned short f2bf(float f) {
    __hip_bfloat16 b = __float2bfloat16(f);
    return *(unsigned short*)&b;
}
// XOR swizzle within a 128-elem bf16 row (16B chunk keyed by row&7).
__device__ __forceinline__ int swzi(int row, int e) {
    return row * 128 + (e ^ ((row & 7) << 3));
}
// Accumulate 8 bf16 (packed uint4) into a[0..7] fp32.
__device__ __forceinline__ void acc8(float* a, uint4 v) {
    a[0] += __uint_as_float(v.x << 16);
    a[1] += __uint_as_float(v.x & 0xffff0000u);
    a[2] += __uint_as_float(v.y << 16);
    a[3] += __uint_as_float(v.y & 0xffff0000u);
    a[4] += __uint_as_float(v.z << 16);
    a[5] += __uint_as_float(v.z & 0xffff0000u);
    a[6] += __uint_as_float(v.w << 16);
    a[7] += __uint_as_float(v.w & 0xffff0000u);
}
__device__ __forceinline__ f32x4v ntload_f4(const float* p) {
    return __builtin_nontemporal_load((const f32x4v*)p);
}
__device__ __forceinline__ void ntstore_u4(unsigned int* p, u32x4 v) {
    __builtin_nontemporal_store(v, (u32x4*)p);
}

// --- prep: pack dst0/dst1 to ushort + W1,W2 -> transposed bf16 --------------
__global__ __launch_bounds__(256) void prep_pack(
    const int* __restrict__ dst0, const int* __restrict__ dst1,
    unsigned short* __restrict__ d0p, unsigned short* __restrict__ d1p,
    const float* __restrict__ W1, const float* __restrict__ W2,
    unsigned short* __restrict__ W1T, unsigned short* __restrict__ W2T,
    int n0, int n1)   // n0=E0/8, n1=E1/8
{
    int i = blockIdx.x * 256 + threadIdx.x;
    if (i < n0) {
        int4 a = ((const int4*)dst0)[i * 2];
        int4 b = ((const int4*)dst0)[i * 2 + 1];
        u32x4 o;
        o.x = (unsigned)a.x | ((unsigned)a.y << 16);
        o.y = (unsigned)a.z | ((unsigned)a.w << 16);
        o.z = (unsigned)b.x | ((unsigned)b.y << 16);
        o.w = (unsigned)b.z | ((unsigned)b.w << 16);
        ((u32x4*)d0p)[i] = o;
    } else if (i < n0 + n1) {
        int j = i - n0;
        int4 a = ((const int4*)dst1)[j * 2];
        int4 b = ((const int4*)dst1)[j * 2 + 1];
        u32x4 o;
        o.x = (unsigned)a.x | ((unsigned)a.y << 16);
        o.y = (unsigned)a.z | ((unsigned)a.w << 16);
        o.z = (unsigned)b.x | ((unsigned)b.y << 16);
        o.w = (unsigned)b.z | ((unsigned)b.w << 16);
        ((u32x4*)d1p)[j] = o;
    } else {
        int j = i - n0 - n1;
        if (j < 128 * 128) {
            int k = j >> 7, n = j & 127;
            W1T[n * 128 + k] = f2bf(W1[j]);
        } else {
            int j2 = j - 128 * 128;
            if (j2 < 128 * 64) {
                int k = j2 >> 6, n = j2 & 63;
                W2T[n * 128 + k] = f2bf(W2[j2]);
            }
        }
    }
}

// --- scan-fill (236 range blocks) + nt h->bf16 cast (rest of grid) ----------
__global__ __launch_bounds__(256) void scan_fill_cast(
    const unsigned short* __restrict__ d0p, const int* __restrict__ src0, int E0,
    const unsigned short* __restrict__ d1p, const int* __restrict__ src1, int E1,
    int* __restrict__ bkt0c, int* __restrict__ cnt0g,
    int* __restrict__ ovf0,  int* __restrict__ ovfc0,
    int* __restrict__ bkt1c, int* __restrict__ cnt1g,
    int* __restrict__ ovf1,  int* __restrict__ ovfc1,
    const float* __restrict__ hf, unsigned int* __restrict__ hbf, int n8)
{
    __shared__ int lists[RPB * LCAP];   // 32 KB
    __shared__ int lcnt[RPB];
    __shared__ int lovf[OVF_CAP];
    __shared__ int lovfc;

    int b = blockIdx.x, t = threadIdx.x;

    if (b < NFB0 + NFB1) {
        const unsigned short* dp; const int* sp;
        int E, D, brange;
        int *bktc, *cntg, *ovfg, *ovfcg;
        if (b < NFB0) {
            brange = b;
            dp = d0p; sp = src0; E = E0; D = D0_CONST;
            bktc = bkt0c; cntg = cnt0g; ovfg = ovf0; ovfcg = ovfc0;
        } else {
            brange = b - NFB0;
            dp = d1p; sp = src1; E = E1; D = D1_CONST;
            bktc = bkt1c; cntg = cnt1g; ovfg = ovf1; ovfcg = ovfc1;
        }
        int dbase = brange * RPB;

        if (t < RPB) lcnt[t] = 0;
        if (t == 0) lovfc = 0;
        __syncthreads();

        // Scan packed dst stream; ranges are 128-aligned so match test is
        // (dst >> 7) == brange.
        int nv = E >> 3;
        const u32x4* dpv = (const u32x4*)dp;
        for (int v = t; v < nv; v += 256) {
            u32x4 pk = dpv[v];
            unsigned wa[4] = {pk.x, pk.y, pk.z, pk.w};
            #pragma unroll
            for (int k2 = 0; k2 < 4; ++k2) {
                unsigned w = wa[k2];
                int lo = (int)(w & 0xffffu);
                int hi = (int)(w >> 16);
                if ((lo >> 7) == brange) {
                    int s = sp[v * 8 + k2 * 2];
                    int dl = lo & 127;
                    int pos = atomicAdd(&lcnt[dl], 1);
                    if (pos < LCAP) lists[(dl << 6) + pos] = s;
                    else {
                        int p2 = atomicAdd(&lovfc, 1);
                        if (p2 < OVF_CAP) lovf[p2] = (dl << 24) | s;
                    }
                }
                if ((hi >> 7) == brange) {
                    int s = sp[v * 8 + k2 * 2 + 1];
                    int dl = hi & 127;
                    int pos = atomicAdd(&lcnt[dl], 1);
                    if (pos < LCAP) lists[(dl << 6) + pos] = s;
                    else {
                        int p2 = atomicAdd(&lovfc, 1);
                        if (p2 < OVF_CAP) lovf[p2] = (dl << 24) | s;
                    }
                }
            }
        }
        __syncthreads();

        // Coalesced flush: counts, lists (uint4), spill.
        if (t < RPB) {
            int d = dbase + t;
            if (d < D) cntg[d] = lcnt[t];
        }
        if (t == 0) ovfcg[brange] = (lovfc > OVF_CAP) ? OVF_CAP : lovfc;
        for (int i = t; i < RPB * LCAP / 4; i += 256)
            ((uint4*)bktc)[(size_t)brange * (RPB * LCAP / 4) + i] =
                ((const uint4*)lists)[i];
        int no = lovfc; if (no > OVF_CAP) no = OVF_CAP;
        for (int i = t; i < no; i += 256)
            ovfg[brange * OVF_CAP + i] = lovf[i];
    } else {
        int i = (b - NFB0 - NFB1) * 256 + t;
        if (i < n8) {
            f32x4v a = ntload_f4(hf + (size_t)i * 8);
            f32x4v c = ntload_f4(hf + (size_t)i * 8 + 4);
            u32x4 o;
            o.x = f2bf(a.x) | ((unsigned)f2bf(a.y) << 16);
            o.y = f2bf(a.z) | ((unsigned)f2bf(a.w) << 16);
            o.z = f2bf(c.x) | ((unsigned)f2bf(c.y) << 16);
            o.w = f2bf(c.z) | ((unsigned)f2bf(c.w) << 16);
            ntstore_u4(hbf + (size_t)i * 4, o);
        }
    }
}

// --- gather0: y0bf[d] = bf16( sum over list d of hbf[s] ) --------------------
// 8 lanes/row, 32B/lane, 4-row unroll => 8 outstanding 16B loads/lane.
__global__ __launch_bounds__(256) void gather0_kernel(
    const uint4* __restrict__ x,       // [N0,16] uint4 view of bf16 [N0,128]
    const int* __restrict__ bktc,      // [NFB0*RPB*LCAP]
    const int* __restrict__ cntg,      // [D0] (real counts)
    const int* __restrict__ ovfg,      // [NFB0*OVF_CAP]
    const int* __restrict__ ovfcg,     // [NFB0]
    uint4* __restrict__ y,             // [D0,16]
    int D)
{
    int tid = blockIdx.x * 256 + threadIdx.x;
    int d = tid >> 3;
    int c = tid & 7;
    if (d >= D) return;
    int n = cntg[d];
    int base = d << 6;
    int nl = (n > LCAP) ? LCAP : n;

    float a[16];
    #pragma unroll
    for (int q = 0; q < 16; ++q) a[q] = 0.f;

    int i = 0;
    for (; i + 4 <= nl; i += 4) {
        int4 s4 = *(const int4*)&bktc[base + i];
        uint4 v0a = x[(size_t)s4.x * 16 + c * 2];
        uint4 v0b = x[(size_t)s4.x * 16 + c * 2 + 1];
        uint4 v1a = x[(size_t)s4.y * 16 + c * 2];
        uint4 v1b = x[(size_t)s4.y * 16 + c * 2 + 1];
        uint4 v2a = x[(size_t)s4.z * 16 + c * 2];
        uint4 v2b = x[(size_t)s4.z * 16 + c * 2 + 1];
        uint4 v3a = x[(size_t)s4.w * 16 + c * 2];
        uint4 v3b = x[(size_t)s4.w * 16 + c * 2 + 1];
        acc8(a, v0a); acc8(a + 8, v0b);
        acc8(a, v1a); acc8(a + 8, v1b);
        acc8(a, v2a); acc8(a + 8, v2b);
        acc8(a, v3a); acc8(a + 8, v3b);
    }
    for (; i < nl; ++i) {
        int s0 = bktc[base + i];
        acc8(a,     x[(size_t)s0 * 16 + c * 2]);
        acc8(a + 8, x[(size_t)s0 * 16 + c * 2 + 1]);
    }
    if (n > LCAP) {            // spill path (practically never taken)
        int br = d >> 7;
        int no = ovfcg[br];
        int dl = d & 127;
        for (int k = 0; k < no; ++k) {
            int e = ovfg[(br << 8) + k];
            if ((e >> 24) == dl) {
                int s0 = e & 0xFFFFFF;
                acc8(a,     x[(size_t)s0 * 16 + c * 2]);
                acc8(a + 8, x[(size_t)s0 * 16 + c * 2 + 1]);
            }
        }
    }

    uint4 o0, o1;
    o0.x = f2bf(a[0])  | ((unsigned)f2bf(a[1])  << 16);
    o0.y = f2bf(a[2])  | ((unsigned)f2bf(a[3])  << 16);
    o0.z = f2bf(a[4])  | ((unsigned)f2bf(a[5])  << 16);
    o0.w = f2bf(a[6])  | ((unsigned)f2bf(a[7])  << 16);
    o1.x = f2bf(a[8])  | ((unsigned)f2bf(a[9])  << 16);
    o1.y = f2bf(a[10]) | ((unsigned)f2bf(a[11]) << 16);
    o1.z = f2bf(a[12]) | ((unsigned)f2bf(a[13]) << 16);
    o1.w = f2bf(a[14]) | ((unsigned)f2bf(a[15]) << 16);
    y[(size_t)d * 16 + c * 2]     = o0;
    y[(size_t)d * 16 + c * 2 + 1] = o1;
}

// --- fused linear: t = bf16( relu(y0@W1 + b1) @ W2 ) via MFMA ---------------
__global__ __launch_bounds__(256) void fused_linear(
    const unsigned short* __restrict__ y0bf,   // [M,128]
    const unsigned short* __restrict__ W1T,    // [128n][128k]
    const unsigned short* __restrict__ W2T,    // [64n][128k]
    const float* __restrict__ b1,              // [128]
    unsigned short* __restrict__ t,            // [M,64]
    int M)
{
    __shared__ unsigned short Ys[128 * 128];
    __shared__ unsigned short W1s[128 * 128];
    __shared__ unsigned short W2s[64 * 128];

    int tid = threadIdx.x;
    int r0 = blockIdx.x * 128;

    for (int idx = tid; idx < 2048; idx += 256) {
        int r = idx >> 4, ch = idx & 15;
        uint4 v = make_uint4(0, 0, 0, 0);
        if (r0 + r < M) v = *(const uint4*)&y0bf[(size_t)(r0 + r) * 128 + ch * 8];
        *(uint4*)&Ys[swzi(r, ch * 8)] = v;
    }
    for (int idx = tid; idx < 2048; idx += 256) {
        int r = idx >> 4, ch = idx & 15;
        *(uint4*)&W1s[swzi(r, ch * 8)] = *(const uint4*)&W1T[r * 128 + ch * 8];
    }
    for (int idx = tid; idx < 1024; idx += 256) {
        int r = idx >> 4, ch = idx & 15;
        *(uint4*)&W2s[swzi(r, ch * 8)] = *(const uint4*)&W2T[r * 128 + ch * 8];
    }
    __syncthreads();

    int w = tid >> 6, lane = tid & 63;
    int lr = lane & 15, lhi = lane >> 4;
    int wr = 32 * w;

    bf16x8 a[2][4];
    #pragma unroll
    for (int m = 0; m < 2; ++m)
        #pragma unroll
        for (int kt = 0; kt < 4; ++kt)
            a[m][kt] = *(bf16x8*)&Ys[swzi(wr + 16 * m + lr, kt * 32 + lhi * 8)];

    f32x4 acc1[2][8];
    #pragma unroll
    for (int m = 0; m < 2; ++m)
        #pragma unroll
        for (int ct = 0; ct < 8; ++ct) acc1[m][ct] = (f32x4)(0.f);

    #pragma unroll
    for (int ct = 0; ct < 8; ++ct) {
        #pragma unroll
        for (int kt = 0; kt < 4; ++kt) {
            bf16x8 b = *(bf16x8*)&W1s[swzi(ct * 16 + lr, kt * 32 + lhi * 8)];
            acc1[0][ct] = __builtin_amdgcn_mfma_f32_16x16x32_bf16(a[0][kt], b, acc1[0][ct], 0, 0, 0);
            acc1[1][ct] = __builtin_amdgcn_mfma_f32_16x16x32_bf16(a[1][kt], b, acc1[1][ct], 0, 0, 0);
        }
    }

    #pragma unroll
    for (int ct = 0; ct < 8; ++ct) {
        float bv = b1[ct * 16 + lr];
        #pragma unroll
        for (int m = 0; m < 2; ++m)
            #pragma unroll
            for (int q = 0; q < 4; ++q) {
                float v = fmaxf(acc1[m][ct][q] + bv, 0.f);
                Ys[swzi(wr + 16 * m + lhi * 4 + q, ct * 16 + lr)] = f2bf(v);
            }
    }

    bf16x8 a2[2][4];
    #pragma unroll
    for (int m = 0; m < 2; ++m)
        #pragma unroll
        for (int kt = 0; kt < 4; ++kt)
            a2[m][kt] = *(bf16x8*)&Ys[swzi(wr + 16 * m + lr, kt * 32 + lhi * 8)];

    f32x4 acc2[2][4];
    #pragma unroll
    for (int m = 0; m < 2; ++m)
        #pragma unroll
        for (int ct = 0; ct < 4; ++ct) acc2[m][ct] = (f32x4)(0.f);

    #pragma unroll
    for (int ct = 0; ct < 4; ++ct) {
        #pragma unroll
        for (int kt = 0; kt < 4; ++kt) {
            bf16x8 b = *(bf16x8*)&W2s[swzi(ct * 16 + lr, kt * 32 + lhi * 8)];
            acc2[0][ct] = __builtin_amdgcn_mfma_f32_16x16x32_bf16(a2[0][kt], b, acc2[0][ct], 0, 0, 0);
            acc2[1][ct] = __builtin_amdgcn_mfma_f32_16x16x32_bf16(a2[1][kt], b, acc2[1][ct], 0, 0, 0);
        }
    }

    #pragma unroll
    for (int m = 0; m < 2; ++m)
        #pragma unroll
        for (int ct = 0; ct < 4; ++ct)
            #pragma unroll
            for (int q = 0; q < 4; ++q) {
                int row = r0 + wr + 16 * m + lhi * 4 + q;
                if (row < M) t[(size_t)row * 64 + ct * 16 + lr] = f2bf(acc2[m][ct][q]);
            }
}

// --- gather1: out[d] = sum over list d of t[s], + b2, f32 out ----------------
__global__ __launch_bounds__(256) void gather1_kernel(
    const uint4* __restrict__ x,       // [M,8] uint4 view of bf16 [M,64]
    const int* __restrict__ bktc,
    const int* __restrict__ cntg,
    const int* __restrict__ ovfg,
    const int* __restrict__ ovfcg,
    const float* __restrict__ b2,
    float4* __restrict__ out,          // [D1,16]
    int D)
{
    int tid = blockIdx.x * 256 + threadIdx.x;
    int d = tid >> 3;
    int c = tid & 7;
    if (d >= D) return;
    int n = cntg[d];
    int base = d << 6;
    int nl = (n > LCAP) ? LCAP : n;

    float a[8] = {0.f, 0.f, 0.f, 0.f, 0.f, 0.f, 0.f, 0.f};
    int i = 0;
    for (; i + 4 <= nl; i += 4) {
        int4 s4 = *(const int4*)&bktc[base + i];
        uint4 v0 = x[(size_t)s4.x * 8 + c];
        uint4 v1 = x[(size_t)s4.y * 8 + c];
        uint4 v2 = x[(size_t)s4.z * 8 + c];
        uint4 v3 = x[(size_t)s4.w * 8 + c];
        acc8(a, v0); acc8(a, v1); acc8(a, v2); acc8(a, v3);
    }
    for (; i < nl; ++i) acc8(a, x[(size_t)bktc[base + i] * 8 + c]);
    if (n > LCAP) {
        int br = d >> 7;
        int no = ovfcg[br];
        int dl = d & 127;
        for (int k = 0; k < no; ++k) {
            int e = ovfg[(br << 8) + k];
            if ((e >> 24) == dl) acc8(a, x[(size_t)(e & 0xFFFFFF) * 8 + c]);
        }
    }

    float4 blo = *(const float4*)&b2[c * 8];
    float4 bhi = *(const float4*)&b2[c * 8 + 4];
    float4 o0 = make_float4(a[0] + blo.x, a[1] + blo.y, a[2] + blo.z, a[3] + blo.w);
    float4 o1 = make_float4(a[4] + bhi.x, a[5] + bhi.y, a[6] + bhi.z, a[7] + bhi.w);
    out[(size_t)d * 16 + c * 2]     = o0;
    out[(size_t)d * 16 + c * 2 + 1] = o1;
}

extern "C" void kernel_launch(void* const* d_in, const int* in_sizes, int n_in,
                              void* d_out, int out_size, void* d_ws, size_t ws_size,
                              hipStream_t stream) {
    const float* h    = (const float*)d_in[0];
    const float* W1   = (const float*)d_in[1];
    const float* b1   = (const float*)d_in[2];
    const float* W2   = (const float*)d_in[3];
    const float* b2   = (const float*)d_in[4];
    const int*   src0 = (const int*)d_in[5];
    const int*   dst0 = (const int*)d_in[6];
    const int*   src1 = (const int*)d_in[7];
    const int*   dst1 = (const int*)d_in[8];

    const int N0 = in_sizes[0] / 128;    // 100000
    const int E0 = in_sizes[5];          // 600000 (multiple of 8)
    const int E1 = in_sizes[7];          // 120000 (multiple of 8)
    const int D0 = D0_CONST;
    const int D1 = D1_CONST;

    // Workspace layout (~45 MB), 16B-aligned blocks.
    char* p = (char*)d_ws;
    unsigned short* hbf  = (unsigned short*)p; p += (size_t)N0 * 128 * 2;   // 25.6 MB
    unsigned short* y0bf = (unsigned short*)p; p += (size_t)D0 * 128 * 2;   // 6.4 MB
    unsigned short* tbf  = (unsigned short*)p; p += (size_t)D0 * 64 * 2;    // 3.2 MB
    unsigned short* W1T  = (unsigned short*)p; p += 128 * 128 * 2;
    unsigned short* W2T  = (unsigned short*)p; p += 64 * 128 * 2;
    unsigned short* d0p  = (unsigned short*)p; p += (size_t)E0 * 2;         // 1.2 MB
    unsigned short* d1p  = (unsigned short*)p; p += (size_t)E1 * 2;         // 0.24 MB
    int* bkt0c = (int*)p; p += (size_t)NFB0 * RPB * LCAP * 4;               // 6.42 MB
    int* bkt1c = (int*)p; p += (size_t)NFB1 * RPB * LCAP * 4;               // 1.31 MB
    int* cnt0g = (int*)p; p += (size_t)D0 * 4;
    int* cnt1g = (int*)p; p += (size_t)D1 * 4;
    int* ovf0  = (int*)p; p += (size_t)NFB0 * OVF_CAP * 4;                  // 0.2 MB
    int* ovf1  = (int*)p; p += (size_t)NFB1 * OVF_CAP * 4;
    int* ovfc0 = (int*)p; p += (size_t)NFB0 * 4;
    int* ovfc1 = (int*)p; p += (size_t)NFB1 * 4;

    float* out = (float*)d_out;

    // 1) pack dst streams to ushort + W transpose/cast.
    {
        int n0 = E0 / 8, n1 = E1 / 8;
        int tot = n0 + n1 + 128 * 128 + 128 * 64;
        prep_pack<<<(tot + 255) / 256, 256, 0, stream>>>(
            dst0, dst1, d0p, d1p, W1, W2, W1T, W2T, n0, n1);
    }

    // 2) scan-fill (236 blocks) + nt h->bf16 cast (co-scheduled).
    {
        int n8 = N0 * 128 / 8;                       // 1.6M
        int castBlocks = (n8 + 255) / 256;
        scan_fill_cast<<<NFB0 + NFB1 + castBlocks, 256, 0, stream>>>(
            d0p, src0, E0, d1p, src1, E1,
            bkt0c, cnt0g, ovf0, ovfc0,
            bkt1c, cnt1g, ovf1, ovfc1,
            h, (unsigned int*)hbf, n8);
    }

    // 3) layer-0 aggregation.
    {
        long long threads = (long long)D0 * 8;
        gather0_kernel<<<(int)((threads + 255) / 256), 256, 0, stream>>>(
            (const uint4*)hbf, bkt0c, cnt0g, ovf0, ovfc0, (uint4*)y0bf, D0);
    }
    // 4) t = relu(y0@W1+b1)@W2
    fused_linear<<<(D0 + 127) / 128, 256, 0, stream>>>(y0bf, W1T, W2T, b1, tbf, D0);

    // 5) layer-1 aggregation + bias -> final output.
    {
        long long threads = (long long)D1 * 8;
        gather1_kernel<<<(int)((threads + 255) / 256), 256, 0, stream>>>(
            (const uint4*)tbf, bkt1c, cnt1g, ovf1, ovfc1, b2, (float4*)out, D1);
    }
}

// Round 11
// 84.531 us; speedup vs baseline: 3.1752x; 3.1752x over previous
//
#include <hip/hip_runtime.h>
#include <hip/hip_bf16.h>

// ---------------------------------------------------------------------------
// SAGEModel fused pipeline (bf16 data path, fp32 accumulation):
//   hbf  = bf16(h)                              [100000,128]
//   y0   = segsum(hbf[src0])  -> bf16           [25000,128]
//   t    = relu(y0@W1+b1)@W2  -> bf16 (MFMA)    [25000,64]
//   out  = segsum(t[src1]) + b2 -> f32          [5000,64]
//
// CSR build (R4-R10 lessons): plain atomic fill is bound by RETURNING-atomic
// throughput (~720k @ ~16G/s = 45us); redundant-scan designs die on a
// 1-block/CU tail. This build does a 2-phase multisplit:
//  Phase 1 (scatter_cast, 176 blocks + cast blocks, 2KB LDS): per-block LDS
//   hist over 236 gdst-ranges -> per-edge rank via LDS atomics; ONE global
//   returning atomic per (block,range) (41k total) reserves a contiguous run;
//   edges written as ~64B runs into per-range regions.
//  Phase 2 (build_csr, 236 blocks): read own region contiguously, LDS-bucket
//   into 128 per-dst lists (64 cap + spill), flush compact CSR coalesced.
// No global memsets, no rescans. gdst = dst0 | 25088+dst1 (unified ranges).
// ---------------------------------------------------------------------------

#define D0_CONST 25000
#define D1_CONST 5000
#define LCAP 64
#define OVF_CAP 256
#define RGN_CAP 4096            // entries per range region (avg 3050, +19 sigma)
#define NRANGE 236              // 196 (layer0) + 40 (layer1)
#define GD1OFF 25088            // 196*128

typedef __attribute__((ext_vector_type(8))) short bf16x8;
typedef __attribute__((ext_vector_type(4))) float f32x4;
typedef __attribute__((ext_vector_type(4))) float f32x4v;
typedef __attribute__((ext_vector_type(4))) unsigned int u32x4;

__device__ __forceinline__ unsigned short f2bf(float f) {
    __hip_bfloat16 b = __float2bfloat16(f);
    return *(unsigned short*)&b;
}
// XOR swizzle within a 128-elem bf16 row (16B chunk keyed by row&7).
__device__ __forceinline__ int swzi(int row, int e) {
    return row * 128 + (e ^ ((row & 7) << 3));
}
// Accumulate 8 bf16 (packed uint4) into a[0..7] fp32.
__device__ __forceinline__ void acc8(float* a, uint4 v) {
    a[0] += __uint_as_float(v.x << 16);
    a[1] += __uint_as_float(v.x & 0xffff0000u);
    a[2] += __uint_as_float(v.y << 16);
    a[3] += __uint_as_float(v.y & 0xffff0000u);
    a[4] += __uint_as_float(v.z << 16);
    a[5] += __uint_as_float(v.z & 0xffff0000u);
    a[6] += __uint_as_float(v.w << 16);
    a[7] += __uint_as_float(v.w & 0xffff0000u);
}
__device__ __forceinline__ f32x4v ntload_f4(const float* p) {
    return __builtin_nontemporal_load((const f32x4v*)p);
}
__device__ __forceinline__ void ntstore_u4(unsigned int* p, u32x4 v) {
    __builtin_nontemporal_store(v, (u32x4*)p);
}

// --- prep: pack gdst (ushort, layer1 offset) + W transpose + cursor init ----
__global__ __launch_bounds__(256) void prep_pack(
    const int* __restrict__ dst0, const int* __restrict__ dst1,
    unsigned short* __restrict__ gdp,
    const float* __restrict__ W1, const float* __restrict__ W2,
    unsigned short* __restrict__ W1T, unsigned short* __restrict__ W2T,
    int* __restrict__ rangecur,
    int n0, int n1)   // n0=E0/8, n1=E1/8
{
    int i = blockIdx.x * 256 + threadIdx.x;
    if (i < n0) {
        int4 a = ((const int4*)dst0)[i * 2];
        int4 b = ((const int4*)dst0)[i * 2 + 1];
        u32x4 o;
        o.x = (unsigned)a.x | ((unsigned)a.y << 16);
        o.y = (unsigned)a.z | ((unsigned)a.w << 16);
        o.z = (unsigned)b.x | ((unsigned)b.y << 16);
        o.w = (unsigned)b.z | ((unsigned)b.w << 16);
        ((u32x4*)gdp)[i] = o;
    } else if (i < n0 + n1) {
        int j = i - n0;
        int4 a = ((const int4*)dst1)[j * 2];
        int4 b = ((const int4*)dst1)[j * 2 + 1];
        u32x4 o;
        o.x = (unsigned)(a.x + GD1OFF) | ((unsigned)(a.y + GD1OFF) << 16);
        o.y = (unsigned)(a.z + GD1OFF) | ((unsigned)(a.w + GD1OFF) << 16);
        o.z = (unsigned)(b.x + GD1OFF) | ((unsigned)(b.y + GD1OFF) << 16);
        o.w = (unsigned)(b.z + GD1OFF) | ((unsigned)(b.w + GD1OFF) << 16);
        ((u32x4*)gdp)[i] = o;
    } else {
        int j = i - n0 - n1;
        if (j < 128 * 128) {
            int k = j >> 7, n = j & 127;
            W1T[n * 128 + k] = f2bf(W1[j]);
        } else if (j < 128 * 128 + 128 * 64) {
            int j2 = j - 128 * 128;
            int k = j2 >> 6, n = j2 & 63;
            W2T[n * 128 + k] = f2bf(W2[j2]);
        } else {
            int k2 = j - 128 * 128 - 128 * 64;
            if (k2 < NRANGE) rangecur[k2] = k2 * RGN_CAP;
        }
    }
}

// --- phase 1: multisplit scatter (LDS ranks, 236 reserves/block) + nt cast --
__global__ __launch_bounds__(256) void scatter_cast(
    const unsigned short* __restrict__ gdp,
    const int* __restrict__ src0, const int* __restrict__ src1,
    int E0, int ET,
    int* __restrict__ rgn, int* __restrict__ rangecur,
    const float* __restrict__ hf, unsigned int* __restrict__ hbf, int n8,
    int nbScat)
{
    __shared__ int hist[256];
    __shared__ int base[256];

    int b = blockIdx.x, t = threadIdx.x;
    if (b < nbScat) {
        hist[t] = 0;
        __syncthreads();

        int eb = b * 4096 + t * 16;
        // 16 gdsts: two coalesced 16B loads.
        const u32x4* gv = (const u32x4*)gdp;
        u32x4 p0 = gv[(size_t)b * 512 + t * 2];
        u32x4 p1 = gv[(size_t)b * 512 + t * 2 + 1];
        unsigned wa[8] = {p0.x, p0.y, p0.z, p0.w, p1.x, p1.y, p1.z, p1.w};
        int g[16], rk[16], dl[16];
        #pragma unroll
        for (int k = 0; k < 16; ++k) {
            unsigned gd = (wa[k >> 1] >> ((k & 1) * 16)) & 0xffffu;
            g[k]  = (int)(gd >> 7);
            dl[k] = (int)(gd & 127u);
            rk[k] = (eb + k < ET) ? atomicAdd(&hist[g[k]], 1) : 0;
        }
        __syncthreads();
        if (t < NRANGE) {
            int c = hist[t];
            base[t] = c ? atomicAdd(&rangecur[t], c) : 0;
        }
        __syncthreads();

        // 16 srcs (vectorized when the span lies in one list).
        int s[16];
        if (eb + 16 <= E0) {
            #pragma unroll
            for (int q = 0; q < 4; ++q) {
                int4 v = ((const int4*)(src0 + eb))[q];
                s[q * 4] = v.x; s[q * 4 + 1] = v.y; s[q * 4 + 2] = v.z; s[q * 4 + 3] = v.w;
            }
        } else if (eb >= E0 && eb + 16 <= ET) {
            const int* sp = src1 + (eb - E0);
            #pragma unroll
            for (int q = 0; q < 4; ++q) {
                int4 v = ((const int4*)sp)[q];
                s[q * 4] = v.x; s[q * 4 + 1] = v.y; s[q * 4 + 2] = v.z; s[q * 4 + 3] = v.w;
            }
        } else {
            #pragma unroll
            for (int k = 0; k < 16; ++k) {
                int e = eb + k;
                s[k] = (e < E0) ? src0[e] : ((e < ET) ? src1[e - E0] : 0);
            }
        }

        #pragma unroll
        for (int k = 0; k < 16; ++k) {
            int e = eb + k;
            if (e < ET) {
                int pos = base[g[k]] + rk[k];
                if (pos < (g[k] + 1) * RGN_CAP)
                    rgn[pos] = (dl[k] << 17) | s[k];
            }
        }
    } else {
        int i = (b - nbScat) * 256 + t;
        if (i < n8) {
            f32x4v a = ntload_f4(hf + (size_t)i * 8);
            f32x4v c = ntload_f4(hf + (size_t)i * 8 + 4);
            u32x4 o;
            o.x = f2bf(a.x) | ((unsigned)f2bf(a.y) << 16);
            o.y = f2bf(a.z) | ((unsigned)f2bf(a.w) << 16);
            o.z = f2bf(c.x) | ((unsigned)f2bf(c.y) << 16);
            o.w = f2bf(c.z) | ((unsigned)f2bf(c.w) << 16);
            ntstore_u4(hbf + (size_t)i * 4, o);
        }
    }
}

// --- phase 2: per-range CSR build (contiguous read, LDS bucket, coalesced) --
__global__ __launch_bounds__(256) void build_csr(
    const int* __restrict__ rgn, const int* __restrict__ rangecur,
    int* __restrict__ bktc,      // [NRANGE*128*64]
    int* __restrict__ cnt,       // [NRANGE*128] (real counts)
    int* __restrict__ ovf, int* __restrict__ ovfc)
{
    __shared__ int lists[128 * LCAP];   // 32 KB
    __shared__ int lcnt[128];
    __shared__ int lovf[OVF_CAP];
    __shared__ int lovfc;

    int g = blockIdx.x, t = threadIdx.x;
    if (t < 128) lcnt[t] = 0;
    if (t == 0) lovfc = 0;
    __syncthreads();

    int n = rangecur[g] - g * RGN_CAP;
    if (n > RGN_CAP) n = RGN_CAP;
    const int* rp = rgn + (size_t)g * RGN_CAP;
    for (int i = t; i < n; i += 256) {
        int e = rp[i];
        int dl = e >> 17;
        int s  = e & 0x1FFFF;
        int r = atomicAdd(&lcnt[dl], 1);
        if (r < LCAP) lists[(dl << 6) + r] = s;
        else {
            int p2 = atomicAdd(&lovfc, 1);
            if (p2 < OVF_CAP) lovf[p2] = (dl << 24) | s;
        }
    }
    __syncthreads();

    if (t < 128) cnt[g * 128 + t] = lcnt[t];
    if (t == 0) ovfc[g] = (lovfc > OVF_CAP) ? OVF_CAP : lovfc;
    for (int i = t; i < 128 * LCAP / 4; i += 256)
        ((uint4*)bktc)[(size_t)g * (128 * LCAP / 4) + i] = ((const uint4*)lists)[i];
    int no = lovfc; if (no > OVF_CAP) no = OVF_CAP;
    for (int i = t; i < no; i += 256) ovf[g * OVF_CAP + i] = lovf[i];
}

// --- gather0: y0bf[d] = bf16( sum over list d of hbf[s] ) --------------------
__global__ __launch_bounds__(256) void gather0_kernel(
    const uint4* __restrict__ x,       // [N0,16] uint4 view of bf16 [N0,128]
    const int* __restrict__ bktc, const int* __restrict__ cntg,
    const int* __restrict__ ovfg, const int* __restrict__ ovfcg,
    uint4* __restrict__ y,             // [D0,16]
    int D)
{
    int tid = blockIdx.x * 256 + threadIdx.x;
    int d = tid >> 3;
    int c = tid & 7;
    if (d >= D) return;
    int n = cntg[d];
    int base = d << 6;
    int nl = (n > LCAP) ? LCAP : n;

    float a[16];
    #pragma unroll
    for (int q = 0; q < 16; ++q) a[q] = 0.f;

    int i = 0;
    for (; i + 4 <= nl; i += 4) {
        int4 s4 = *(const int4*)&bktc[base + i];
        uint4 v0a = x[(size_t)s4.x * 16 + c * 2];
        uint4 v0b = x[(size_t)s4.x * 16 + c * 2 + 1];
        uint4 v1a = x[(size_t)s4.y * 16 + c * 2];
        uint4 v1b = x[(size_t)s4.y * 16 + c * 2 + 1];
        uint4 v2a = x[(size_t)s4.z * 16 + c * 2];
        uint4 v2b = x[(size_t)s4.z * 16 + c * 2 + 1];
        uint4 v3a = x[(size_t)s4.w * 16 + c * 2];
        uint4 v3b = x[(size_t)s4.w * 16 + c * 2 + 1];
        acc8(a, v0a); acc8(a + 8, v0b);
        acc8(a, v1a); acc8(a + 8, v1b);
        acc8(a, v2a); acc8(a + 8, v2b);
        acc8(a, v3a); acc8(a + 8, v3b);
    }
    for (; i < nl; ++i) {
        int s0 = bktc[base + i];
        acc8(a,     x[(size_t)s0 * 16 + c * 2]);
        acc8(a + 8, x[(size_t)s0 * 16 + c * 2 + 1]);
    }
    if (n > LCAP) {            // spill (statistically never, correctness-safe)
        int br = d >> 7;
        int no = ovfcg[br];
        int dl = d & 127;
        for (int k = 0; k < no; ++k) {
            int e = ovfg[(br << 8) + k];
            if ((e >> 24) == dl) {
                int s0 = e & 0xFFFFFF;
                acc8(a,     x[(size_t)s0 * 16 + c * 2]);
                acc8(a + 8, x[(size_t)s0 * 16 + c * 2 + 1]);
            }
        }
    }

    uint4 o0, o1;
    o0.x = f2bf(a[0])  | ((unsigned)f2bf(a[1])  << 16);
    o0.y = f2bf(a[2])  | ((unsigned)f2bf(a[3])  << 16);
    o0.z = f2bf(a[4])  | ((unsigned)f2bf(a[5])  << 16);
    o0.w = f2bf(a[6])  | ((unsigned)f2bf(a[7])  << 16);
    o1.x = f2bf(a[8])  | ((unsigned)f2bf(a[9])  << 16);
    o1.y = f2bf(a[10]) | ((unsigned)f2bf(a[11]) << 16);
    o1.z = f2bf(a[12]) | ((unsigned)f2bf(a[13]) << 16);
    o1.w = f2bf(a[14]) | ((unsigned)f2bf(a[15]) << 16);
    y[(size_t)d * 16 + c * 2]     = o0;
    y[(size_t)d * 16 + c * 2 + 1] = o1;
}

// --- fused linear: t = bf16( relu(y0@W1 + b1) @ W2 ) via MFMA ---------------
__global__ __launch_bounds__(256) void fused_linear(
    const unsigned short* __restrict__ y0bf,   // [M,128]
    const unsigned short* __restrict__ W1T,    // [128n][128k]
    const unsigned short* __restrict__ W2T,    // [64n][128k]
    const float* __restrict__ b1,              // [128]
    unsigned short* __restrict__ t,            // [M,64]
    int M)
{
    __shared__ unsigned short Ys[128 * 128];
    __shared__ unsigned short W1s[128 * 128];
    __shared__ unsigned short W2s[64 * 128];

    int tid = threadIdx.x;
    int r0 = blockIdx.x * 128;

    for (int idx = tid; idx < 2048; idx += 256) {
        int r = idx >> 4, ch = idx & 15;
        uint4 v = make_uint4(0, 0, 0, 0);
        if (r0 + r < M) v = *(const uint4*)&y0bf[(size_t)(r0 + r) * 128 + ch * 8];
        *(uint4*)&Ys[swzi(r, ch * 8)] = v;
    }
    for (int idx = tid; idx < 2048; idx += 256) {
        int r = idx >> 4, ch = idx & 15;
        *(uint4*)&W1s[swzi(r, ch * 8)] = *(const uint4*)&W1T[r * 128 + ch * 8];
    }
    for (int idx = tid; idx < 1024; idx += 256) {
        int r = idx >> 4, ch = idx & 15;
        *(uint4*)&W2s[swzi(r, ch * 8)] = *(const uint4*)&W2T[r * 128 + ch * 8];
    }
    __syncthreads();

    int w = tid >> 6, lane = tid & 63;
    int lr = lane & 15, lhi = lane >> 4;
    int wr = 32 * w;

    bf16x8 a[2][4];
    #pragma unroll
    for (int m = 0; m < 2; ++m)
        #pragma unroll
        for (int kt = 0; kt < 4; ++kt)
            a[m][kt] = *(bf16x8*)&Ys[swzi(wr + 16 * m + lr, kt * 32 + lhi * 8)];

    f32x4 acc1[2][8];
    #pragma unroll
    for (int m = 0; m < 2; ++m)
        #pragma unroll
        for (int ct = 0; ct < 8; ++ct) acc1[m][ct] = (f32x4)(0.f);

    #pragma unroll
    for (int ct = 0; ct < 8; ++ct) {
        #pragma unroll
        for (int kt = 0; kt < 4; ++kt) {
            bf16x8 b = *(bf16x8*)&W1s[swzi(ct * 16 + lr, kt * 32 + lhi * 8)];
            acc1[0][ct] = __builtin_amdgcn_mfma_f32_16x16x32_bf16(a[0][kt], b, acc1[0][ct], 0, 0, 0);
            acc1[1][ct] = __builtin_amdgcn_mfma_f32_16x16x32_bf16(a[1][kt], b, acc1[1][ct], 0, 0, 0);
        }
    }

    #pragma unroll
    for (int ct = 0; ct < 8; ++ct) {
        float bv = b1[ct * 16 + lr];
        #pragma unroll
        for (int m = 0; m < 2; ++m)
            #pragma unroll
            for (int q = 0; q < 4; ++q) {
                float v = fmaxf(acc1[m][ct][q] + bv, 0.f);
                Ys[swzi(wr + 16 * m + lhi * 4 + q, ct * 16 + lr)] = f2bf(v);
            }
    }

    bf16x8 a2[2][4];
    #pragma unroll
    for (int m = 0; m < 2; ++m)
        #pragma unroll
        for (int kt = 0; kt < 4; ++kt)
            a2[m][kt] = *(bf16x8*)&Ys[swzi(wr + 16 * m + lr, kt * 32 + lhi * 8)];

    f32x4 acc2[2][4];
    #pragma unroll
    for (int m = 0; m < 2; ++m)
        #pragma unroll
        for (int ct = 0; ct < 4; ++ct) acc2[m][ct] = (f32x4)(0.f);

    #pragma unroll
    for (int ct = 0; ct < 4; ++ct) {
        #pragma unroll
        for (int kt = 0; kt < 4; ++kt) {
            bf16x8 b = *(bf16x8*)&W2s[swzi(ct * 16 + lr, kt * 32 + lhi * 8)];
            acc2[0][ct] = __builtin_amdgcn_mfma_f32_16x16x32_bf16(a2[0][kt], b, acc2[0][ct], 0, 0, 0);
            acc2[1][ct] = __builtin_amdgcn_mfma_f32_16x16x32_bf16(a2[1][kt], b, acc2[1][ct], 0, 0, 0);
        }
    }

    #pragma unroll
    for (int m = 0; m < 2; ++m)
        #pragma unroll
        for (int ct = 0; ct < 4; ++ct)
            #pragma unroll
            for (int q = 0; q < 4; ++q) {
                int row = r0 + wr + 16 * m + lhi * 4 + q;
                if (row < M) t[(size_t)row * 64 + ct * 16 + lr] = f2bf(acc2[m][ct][q]);
            }
}

// --- gather1: out[d] = sum over list (GD1OFF+d) of t[s], + b2 ----------------
__global__ __launch_bounds__(256) void gather1_kernel(
    const uint4* __restrict__ x,       // [M,8] uint4 view of bf16 [M,64]
    const int* __restrict__ bktc, const int* __restrict__ cntg,
    const int* __restrict__ ovfg, const int* __restrict__ ovfcg,
    const float* __restrict__ b2,
    float4* __restrict__ out,          // [D1,16]
    int D)
{
    int tid = blockIdx.x * 256 + threadIdx.x;
    int d = tid >> 3;
    int c = tid & 7;
    if (d >= D) return;
    int gd = GD1OFF + d;
    int n = cntg[gd];
    int base = gd << 6;
    int nl = (n > LCAP) ? LCAP : n;

    float a[8] = {0.f, 0.f, 0.f, 0.f, 0.f, 0.f, 0.f, 0.f};
    int i = 0;
    for (; i + 4 <= nl; i += 4) {
        int4 s4 = *(const int4*)&bktc[base + i];
        uint4 v0 = x[(size_t)s4.x * 8 + c];
        uint4 v1 = x[(size_t)s4.y * 8 + c];
        uint4 v2 = x[(size_t)s4.z * 8 + c];
        uint4 v3 = x[(size_t)s4.w * 8 + c];
        acc8(a, v0); acc8(a, v1); acc8(a, v2); acc8(a, v3);
    }
    for (; i < nl; ++i) acc8(a, x[(size_t)bktc[base + i] * 8 + c]);
    if (n > LCAP) {
        int br = gd >> 7;
        int no = ovfcg[br];
        int dl = gd & 127;
        for (int k = 0; k < no; ++k) {
            int e = ovfg[(br << 8) + k];
            if ((e >> 24) == dl) acc8(a, x[(size_t)(e & 0xFFFFFF) * 8 + c]);
        }
    }

    float4 blo = *(const float4*)&b2[c * 8];
    float4 bhi = *(const float4*)&b2[c * 8 + 4];
    float4 o0 = make_float4(a[0] + blo.x, a[1] + blo.y, a[2] + blo.z, a[3] + blo.w);
    float4 o1 = make_float4(a[4] + bhi.x, a[5] + bhi.y, a[6] + bhi.z, a[7] + bhi.w);
    out[(size_t)d * 16 + c * 2]     = o0;
    out[(size_t)d * 16 + c * 2 + 1] = o1;
}

extern "C" void kernel_launch(void* const* d_in, const int* in_sizes, int n_in,
                              void* d_out, int out_size, void* d_ws, size_t ws_size,
                              hipStream_t stream) {
    const float* h    = (const float*)d_in[0];
    const float* W1   = (const float*)d_in[1];
    const float* b1   = (const float*)d_in[2];
    const float* W2   = (const float*)d_in[3];
    const float* b2   = (const float*)d_in[4];
    const int*   src0 = (const int*)d_in[5];
    const int*   dst0 = (const int*)d_in[6];
    const int*   src1 = (const int*)d_in[7];
    const int*   dst1 = (const int*)d_in[8];

    const int N0 = in_sizes[0] / 128;    // 100000
    const int E0 = in_sizes[5];          // 600000 (multiple of 8)
    const int E1 = in_sizes[7];          // 120000 (multiple of 8)
    const int ET = E0 + E1;
    const int D0 = D0_CONST;
    const int D1 = D1_CONST;
    const int nbScat = (ET + 4095) / 4096;   // 176

    // Workspace layout (~49 MB), 16B-aligned blocks.
    char* p = (char*)d_ws;
    unsigned short* hbf  = (unsigned short*)p; p += (size_t)N0 * 128 * 2;   // 25.6 MB
    unsigned short* y0bf = (unsigned short*)p; p += (size_t)D0 * 128 * 2;   // 6.4 MB
    unsigned short* tbf  = (unsigned short*)p; p += (size_t)D0 * 64 * 2;    // 3.2 MB
    unsigned short* W1T  = (unsigned short*)p; p += 128 * 128 * 2;
    unsigned short* W2T  = (unsigned short*)p; p += 64 * 128 * 2;
    unsigned short* gdp  = (unsigned short*)p; p += (size_t)nbScat * 4096 * 2; // 1.44 MB (padded)
    int* rgn      = (int*)p; p += (size_t)NRANGE * RGN_CAP * 4;             // 3.87 MB
    int* bktc     = (int*)p; p += (size_t)NRANGE * 128 * LCAP * 4;          // 7.73 MB
    int* cntg     = (int*)p; p += (size_t)NRANGE * 128 * 4;                 // 121 KB
    int* rangecur = (int*)p; p += 256 * 4;
    int* ovf      = (int*)p; p += (size_t)NRANGE * OVF_CAP * 4;             // 242 KB
    int* ovfc     = (int*)p; p += 256 * 4;

    float* out = (float*)d_out;

    // 1) pack gdst + W transpose/cast + range-cursor init (no memsets).
    {
        int n0 = E0 / 8, n1 = E1 / 8;
        int tot = n0 + n1 + 128 * 128 + 128 * 64 + NRANGE;
        prep_pack<<<(tot + 255) / 256, 256, 0, stream>>>(
            dst0, dst1, gdp, W1, W2, W1T, W2T, rangecur, n0, n1);
    }

    // 2) phase-1 multisplit scatter + nt h->bf16 cast (co-scheduled).
    {
        int n8 = N0 * 128 / 8;                       // 1.6M
        int castBlocks = (n8 + 255) / 256;
        scatter_cast<<<nbScat + castBlocks, 256, 0, stream>>>(
            gdp, src0, src1, E0, ET, rgn, rangecur,
            h, (unsigned int*)hbf, n8, nbScat);
    }

    // 3) phase-2 per-range CSR build.
    build_csr<<<NRANGE, 256, 0, stream>>>(rgn, rangecur, bktc, cntg, ovf, ovfc);

    // 4) layer-0 aggregation.
    {
        long long threads = (long long)D0 * 8;
        gather0_kernel<<<(int)((threads + 255) / 256), 256, 0, stream>>>(
            (const uint4*)hbf, bktc, cntg, ovf, ovfc, (uint4*)y0bf, D0);
    }
    // 5) t = relu(y0@W1+b1)@W2
    fused_linear<<<(D0 + 127) / 128, 256, 0, stream>>>(y0bf, W1T, W2T, b1, tbf, D0);

    // 6) layer-1 aggregation + bias -> final output.
    {
        long long threads = (long long)D1 * 8;
        gather1_kernel<<<(int)((threads + 255) / 256), 256, 0, stream>>>(
            (const uint4*)tbf, bktc, cntg, ovf, ovfc, b2, (float4*)out, D1);
    }
}

// Round 12
// 75.263 us; speedup vs baseline: 3.5661x; 1.1231x over previous
//
#include <hip/hip_runtime.h>
#include <hip/hip_bf16.h>

// ---------------------------------------------------------------------------
// SAGEModel fused pipeline (bf16 data path, fp32 accumulation):
//   hbf  = bf16(h)                              [100000,128]
//   y0   = segsum(hbf[src0])                    (kept in LDS/registers only)
//   t    = relu(y0@W1+b1)@W2  -> bf16 (MFMA)    [25000,64]
//   out  = segsum(t[src1]) + b2 -> f32          [5000,64]
//
// R11 structure (2-phase multisplit: LDS-rank scatter with 1 returning
// atomic per (block,range)) kept. R12 fuses the rest: per-range regions are
// consumed DIRECTLY by the aggregation kernels (each 32-row block scans its
// range's region, LDS-buckets its own dsts, gathers, and for layer 0 runs
// the relu(y0@W1+b1)@W2 MFMA epilogue in-block, W frags read from L2).
// No CSR materialization, no y0 materialization. 4 dispatches.
// ---------------------------------------------------------------------------

#define D0_CONST 25000
#define D1_CONST 5000
#define LCAP 64
#define OVFB 64                 // per-block LDS spill capacity
#define RGN_CAP 4096            // entries per range region (avg 3050, +19 sigma)
#define NRANGE 236              // 196 (layer0) + 40 (layer1)
#define GD1OFF 25088            // 196*128

typedef __attribute__((ext_vector_type(8))) short bf16x8;
typedef __attribute__((ext_vector_type(4))) float f32x4;
typedef __attribute__((ext_vector_type(4))) float f32x4v;
typedef __attribute__((ext_vector_type(4))) unsigned int u32x4;

__device__ __forceinline__ unsigned short f2bf(float f) {
    __hip_bfloat16 b = __float2bfloat16(f);
    return *(unsigned short*)&b;
}
// XOR swizzle within a 128-elem bf16 row (16B chunk keyed by row&7).
__device__ __forceinline__ int swzi(int row, int e) {
    return row * 128 + (e ^ ((row & 7) << 3));
}
// Accumulate 8 bf16 (packed uint4) into a[0..7] fp32.
__device__ __forceinline__ void acc8(float* a, uint4 v) {
    a[0] += __uint_as_float(v.x << 16);
    a[1] += __uint_as_float(v.x & 0xffff0000u);
    a[2] += __uint_as_float(v.y << 16);
    a[3] += __uint_as_float(v.y & 0xffff0000u);
    a[4] += __uint_as_float(v.z << 16);
    a[5] += __uint_as_float(v.z & 0xffff0000u);
    a[6] += __uint_as_float(v.w << 16);
    a[7] += __uint_as_float(v.w & 0xffff0000u);
}
__device__ __forceinline__ f32x4v ntload_f4(const float* p) {
    return __builtin_nontemporal_load((const f32x4v*)p);
}
__device__ __forceinline__ void ntstore_u4(unsigned int* p, u32x4 v) {
    __builtin_nontemporal_store(v, (u32x4*)p);
}

// --- prep: pack gdst (ushort, layer1 offset) + W transpose + cursor init ----
__global__ __launch_bounds__(256) void prep_pack(
    const int* __restrict__ dst0, const int* __restrict__ dst1,
    unsigned short* __restrict__ gdp,
    const float* __restrict__ W1, const float* __restrict__ W2,
    unsigned short* __restrict__ W1T, unsigned short* __restrict__ W2T,
    int* __restrict__ rangecur,
    int n0, int n1)   // n0=E0/8, n1=E1/8
{
    int i = blockIdx.x * 256 + threadIdx.x;
    if (i < n0) {
        int4 a = ((const int4*)dst0)[i * 2];
        int4 b = ((const int4*)dst0)[i * 2 + 1];
        u32x4 o;
        o.x = (unsigned)a.x | ((unsigned)a.y << 16);
        o.y = (unsigned)a.z | ((unsigned)a.w << 16);
        o.z = (unsigned)b.x | ((unsigned)b.y << 16);
        o.w = (unsigned)b.z | ((unsigned)b.w << 16);
        ((u32x4*)gdp)[i] = o;
    } else if (i < n0 + n1) {
        int j = i - n0;
        int4 a = ((const int4*)dst1)[j * 2];
        int4 b = ((const int4*)dst1)[j * 2 + 1];
        u32x4 o;
        o.x = (unsigned)(a.x + GD1OFF) | ((unsigned)(a.y + GD1OFF) << 16);
        o.y = (unsigned)(a.z + GD1OFF) | ((unsigned)(a.w + GD1OFF) << 16);
        o.z = (unsigned)(b.x + GD1OFF) | ((unsigned)(b.y + GD1OFF) << 16);
        o.w = (unsigned)(b.z + GD1OFF) | ((unsigned)(b.w + GD1OFF) << 16);
        ((u32x4*)gdp)[i] = o;
    } else {
        int j = i - n0 - n1;
        if (j < 128 * 128) {
            int k = j >> 7, n = j & 127;
            W1T[n * 128 + k] = f2bf(W1[j]);
        } else if (j < 128 * 128 + 128 * 64) {
            int j2 = j - 128 * 128;
            int k = j2 >> 6, n = j2 & 63;
            W2T[n * 128 + k] = f2bf(W2[j2]);
        } else {
            int k2 = j - 128 * 128 - 128 * 64;
            if (k2 < NRANGE) rangecur[k2] = k2 * RGN_CAP;
        }
    }
}

// --- phase 1: multisplit scatter (LDS ranks, 236 reserves/block) + nt cast --
__global__ __launch_bounds__(256) void scatter_cast(
    const unsigned short* __restrict__ gdp,
    const int* __restrict__ src0, const int* __restrict__ src1,
    int E0, int ET,
    int* __restrict__ rgn, int* __restrict__ rangecur,
    const float* __restrict__ hf, unsigned int* __restrict__ hbf, int n8,
    int nbScat)
{
    __shared__ int hist[512];
    __shared__ int base[512];

    int b = blockIdx.x, t = threadIdx.x;
    if (b < nbScat) {
        hist[t] = 0; hist[t + 256] = 0;
        __syncthreads();

        int eb = b * 4096 + t * 16;
        const u32x4* gv = (const u32x4*)gdp;
        u32x4 p0 = gv[(size_t)b * 512 + t * 2];
        u32x4 p1 = gv[(size_t)b * 512 + t * 2 + 1];
        unsigned wa[8] = {p0.x, p0.y, p0.z, p0.w, p1.x, p1.y, p1.z, p1.w};
        int g[16], rk[16], dl[16];
        #pragma unroll
        for (int k = 0; k < 16; ++k) {
            unsigned gd = (wa[k >> 1] >> ((k & 1) * 16)) & 0xffffu;
            g[k]  = (int)(gd >> 7);
            dl[k] = (int)(gd & 127u);
            rk[k] = (eb + k < ET) ? atomicAdd(&hist[g[k]], 1) : 0;
        }
        __syncthreads();
        if (t < NRANGE) {
            int c = hist[t];
            base[t] = c ? atomicAdd(&rangecur[t], c) : 0;
        }
        __syncthreads();

        int s[16];
        if (eb + 16 <= E0) {
            #pragma unroll
            for (int q = 0; q < 4; ++q) {
                int4 v = ((const int4*)(src0 + eb))[q];
                s[q * 4] = v.x; s[q * 4 + 1] = v.y; s[q * 4 + 2] = v.z; s[q * 4 + 3] = v.w;
            }
        } else if (eb >= E0 && eb + 16 <= ET) {
            const int* sp = src1 + (eb - E0);
            #pragma unroll
            for (int q = 0; q < 4; ++q) {
                int4 v = ((const int4*)sp)[q];
                s[q * 4] = v.x; s[q * 4 + 1] = v.y; s[q * 4 + 2] = v.z; s[q * 4 + 3] = v.w;
            }
        } else {
            #pragma unroll
            for (int k = 0; k < 16; ++k) {
                int e = eb + k;
                s[k] = (e < E0) ? src0[e] : ((e < ET) ? src1[e - E0] : 0);
            }
        }

        #pragma unroll
        for (int k = 0; k < 16; ++k) {
            int e = eb + k;
            if (e < ET) {
                int pos = base[g[k]] + rk[k];
                if (pos < (g[k] + 1) * RGN_CAP)
                    rgn[pos] = (dl[k] << 17) | s[k];
            }
        }
    } else {
        int i = (b - nbScat) * 256 + t;
        if (i < n8) {
            f32x4v a = ntload_f4(hf + (size_t)i * 8);
            f32x4v c = ntload_f4(hf + (size_t)i * 8 + 4);
            u32x4 o;
            o.x = f2bf(a.x) | ((unsigned)f2bf(a.y) << 16);
            o.y = f2bf(a.z) | ((unsigned)f2bf(a.w) << 16);
            o.z = f2bf(c.x) | ((unsigned)f2bf(c.y) << 16);
            o.w = f2bf(c.z) | ((unsigned)f2bf(c.w) << 16);
            ntstore_u4(hbf + (size_t)i * 4, o);
        }
    }
}

// --- layer 0 fused: bucket own 32 dsts from region, gather, relu-GEMM-GEMM --
// Block b: rows [32b, 32b+32), range g=b>>2, quarter sub=b&3.
__global__ __launch_bounds__(256) void gather0_linear(
    const uint4* __restrict__ x,        // hbf as [N0][16] uint4
    const int* __restrict__ rgn, const int* __restrict__ rangecur,
    const unsigned short* __restrict__ W1T,   // [128n][128k]
    const unsigned short* __restrict__ W2T,   // [64n][128k]
    const float* __restrict__ b1,
    unsigned short* __restrict__ t,     // [M,64]
    int M)
{
    __shared__ int lists[32 * LCAP];          // 8 KB
    __shared__ int lcnt[32];
    __shared__ int lovf[OVFB];
    __shared__ int lovfc;
    __shared__ unsigned short Ys[32 * 128];   // 8 KB
    __shared__ unsigned short H1s[32 * 128];  // 8 KB

    int b = blockIdx.x, tid = threadIdx.x;
    int row0 = b * 32;
    int g = row0 >> 7;
    int sub = (row0 >> 5) & 3;

    if (tid < 32) lcnt[tid] = 0;
    if (tid == 0) lovfc = 0;
    __syncthreads();

    // Scan this range's region; keep only our 32-dst quarter.
    int n = rangecur[g] - g * RGN_CAP;
    if (n > RGN_CAP) n = RGN_CAP;
    const int* rp = rgn + (size_t)g * RGN_CAP;
    for (int i = tid; i < n; i += 256) {
        int e = rp[i];
        if ((e >> 22) == sub) {
            int dl = (e >> 17) & 31;
            int s  = e & 0x1FFFF;
            int r = atomicAdd(&lcnt[dl], 1);
            if (r < LCAP) lists[(dl << 6) + r] = s;
            else {
                int p2 = atomicAdd(&lovfc, 1);
                if (p2 < OVFB) lovf[p2] = (dl << 17) | s;
            }
        }
    }
    __syncthreads();

    // Gather: thread -> (lrow = tid>>3, 32B chunk c = tid&7), sums -> Ys LDS.
    {
        int lrow = tid >> 3, c = tid & 7;
        int nn = lcnt[lrow]; if (nn > LCAP) nn = LCAP;
        const int* lp = &lists[lrow << 6];
        float a[16];
        #pragma unroll
        for (int q = 0; q < 16; ++q) a[q] = 0.f;

        int i = 0;
        for (; i + 4 <= nn; i += 4) {
            int4 s4 = *(const int4*)&lp[i];
            uint4 v0a = x[(size_t)s4.x * 16 + c * 2];
            uint4 v0b = x[(size_t)s4.x * 16 + c * 2 + 1];
            uint4 v1a = x[(size_t)s4.y * 16 + c * 2];
            uint4 v1b = x[(size_t)s4.y * 16 + c * 2 + 1];
            uint4 v2a = x[(size_t)s4.z * 16 + c * 2];
            uint4 v2b = x[(size_t)s4.z * 16 + c * 2 + 1];
            uint4 v3a = x[(size_t)s4.w * 16 + c * 2];
            uint4 v3b = x[(size_t)s4.w * 16 + c * 2 + 1];
            acc8(a, v0a); acc8(a + 8, v0b);
            acc8(a, v1a); acc8(a + 8, v1b);
            acc8(a, v2a); acc8(a + 8, v2b);
            acc8(a, v3a); acc8(a + 8, v3b);
        }
        for (; i < nn; ++i) {
            int s0 = lp[i];
            acc8(a,     x[(size_t)s0 * 16 + c * 2]);
            acc8(a + 8, x[(size_t)s0 * 16 + c * 2 + 1]);
        }
        int no = lovfc; if (no > OVFB) no = OVFB;
        for (int k2 = 0; k2 < no; ++k2) {
            int e = lovf[k2];
            if ((e >> 17) == lrow) {
                int s0 = e & 0x1FFFF;
                acc8(a,     x[(size_t)s0 * 16 + c * 2]);
                acc8(a + 8, x[(size_t)s0 * 16 + c * 2 + 1]);
            }
        }
        uint4 o0, o1;
        o0.x = f2bf(a[0])  | ((unsigned)f2bf(a[1])  << 16);
        o0.y = f2bf(a[2])  | ((unsigned)f2bf(a[3])  << 16);
        o0.z = f2bf(a[4])  | ((unsigned)f2bf(a[5])  << 16);
        o0.w = f2bf(a[6])  | ((unsigned)f2bf(a[7])  << 16);
        o1.x = f2bf(a[8])  | ((unsigned)f2bf(a[9])  << 16);
        o1.y = f2bf(a[10]) | ((unsigned)f2bf(a[11]) << 16);
        o1.z = f2bf(a[12]) | ((unsigned)f2bf(a[13]) << 16);
        o1.w = f2bf(a[14]) | ((unsigned)f2bf(a[15]) << 16);
        *(uint4*)&Ys[swzi(lrow, c * 16)]     = o0;
        *(uint4*)&Ys[swzi(lrow, c * 16 + 8)] = o1;
    }
    __syncthreads();

    // MFMA epilogue. Wave w: GEMM1 cols [32w,32w+32) (ct=2w+j), GEMM2 cols
    // [16w,16w+16). W fragments read straight from L2 (shared across blocks).
    int w = tid >> 6, lane = tid & 63;
    int lr = lane & 15, lhi = lane >> 4;

    bf16x8 a1[2][4];
    #pragma unroll
    for (int m = 0; m < 2; ++m)
        #pragma unroll
        for (int kt = 0; kt < 4; ++kt)
            a1[m][kt] = *(bf16x8*)&Ys[swzi(16 * m + lr, kt * 32 + lhi * 8)];

    f32x4 acc1[2][2];
    #pragma unroll
    for (int m = 0; m < 2; ++m)
        #pragma unroll
        for (int j = 0; j < 2; ++j) acc1[m][j] = (f32x4)(0.f);

    #pragma unroll
    for (int j = 0; j < 2; ++j) {
        int ct = 2 * w + j;
        #pragma unroll
        for (int kt = 0; kt < 4; ++kt) {
            bf16x8 bb = *(const bf16x8*)&W1T[(ct * 16 + lr) * 128 + kt * 32 + lhi * 8];
            acc1[0][j] = __builtin_amdgcn_mfma_f32_16x16x32_bf16(a1[0][kt], bb, acc1[0][j], 0, 0, 0);
            acc1[1][j] = __builtin_amdgcn_mfma_f32_16x16x32_bf16(a1[1][kt], bb, acc1[1][j], 0, 0, 0);
        }
    }

    #pragma unroll
    for (int j = 0; j < 2; ++j) {
        int ct = 2 * w + j;
        float bv = b1[ct * 16 + lr];
        #pragma unroll
        for (int m = 0; m < 2; ++m)
            #pragma unroll
            for (int q = 0; q < 4; ++q) {
                float v = fmaxf(acc1[m][j][q] + bv, 0.f);
                H1s[swzi(16 * m + lhi * 4 + q, ct * 16 + lr)] = f2bf(v);
            }
    }
    __syncthreads();

    bf16x8 a2[2][4];
    #pragma unroll
    for (int m = 0; m < 2; ++m)
        #pragma unroll
        for (int kt = 0; kt < 4; ++kt)
            a2[m][kt] = *(bf16x8*)&H1s[swzi(16 * m + lr, kt * 32 + lhi * 8)];

    f32x4 acc2[2];
    acc2[0] = (f32x4)(0.f); acc2[1] = (f32x4)(0.f);
    #pragma unroll
    for (int kt = 0; kt < 4; ++kt) {
        bf16x8 bb = *(const bf16x8*)&W2T[(w * 16 + lr) * 128 + kt * 32 + lhi * 8];
        acc2[0] = __builtin_amdgcn_mfma_f32_16x16x32_bf16(a2[0][kt], bb, acc2[0], 0, 0, 0);
        acc2[1] = __builtin_amdgcn_mfma_f32_16x16x32_bf16(a2[1][kt], bb, acc2[1], 0, 0, 0);
    }

    #pragma unroll
    for (int m = 0; m < 2; ++m)
        #pragma unroll
        for (int q = 0; q < 4; ++q) {
            int row = row0 + 16 * m + lhi * 4 + q;
            if (row < M) t[(size_t)row * 64 + w * 16 + lr] = f2bf(acc2[m][q]);
        }
}

// --- layer 1 fused: bucket own 32 dsts from region, gather from t, + b2 -----
__global__ __launch_bounds__(256) void gather1_kernel(
    const uint4* __restrict__ x,       // [M,8] uint4 view of bf16 t [M,64]
    const int* __restrict__ rgn, const int* __restrict__ rangecur,
    const float* __restrict__ b2,
    float4* __restrict__ out,          // [D1,16]
    int D)
{
    __shared__ int lists[32 * LCAP];   // 8 KB
    __shared__ int lcnt[32];
    __shared__ int lovf[OVFB];
    __shared__ int lovfc;

    int b = blockIdx.x, tid = threadIdx.x;
    int row0 = b * 32;
    int g = 196 + (row0 >> 7);
    int sub = (row0 >> 5) & 3;

    if (tid < 32) lcnt[tid] = 0;
    if (tid == 0) lovfc = 0;
    __syncthreads();

    int n = rangecur[g] - g * RGN_CAP;
    if (n > RGN_CAP) n = RGN_CAP;
    const int* rp = rgn + (size_t)g * RGN_CAP;
    for (int i = tid; i < n; i += 256) {
        int e = rp[i];
        if ((e >> 22) == sub) {
            int dl = (e >> 17) & 31;
            int s  = e & 0x1FFFF;
            int r = atomicAdd(&lcnt[dl], 1);
            if (r < LCAP) lists[(dl << 6) + r] = s;
            else {
                int p2 = atomicAdd(&lovfc, 1);
                if (p2 < OVFB) lovf[p2] = (dl << 17) | s;
            }
        }
    }
    __syncthreads();

    int lrow = tid >> 3, c = tid & 7;
    int d = row0 + lrow;
    if (d >= D) return;
    int nn = lcnt[lrow]; if (nn > LCAP) nn = LCAP;
    const int* lp = &lists[lrow << 6];

    float a[8] = {0.f, 0.f, 0.f, 0.f, 0.f, 0.f, 0.f, 0.f};
    int i = 0;
    for (; i + 4 <= nn; i += 4) {
        int4 s4 = *(const int4*)&lp[i];
        uint4 v0 = x[(size_t)s4.x * 8 + c];
        uint4 v1 = x[(size_t)s4.y * 8 + c];
        uint4 v2 = x[(size_t)s4.z * 8 + c];
        uint4 v3 = x[(size_t)s4.w * 8 + c];
        acc8(a, v0); acc8(a, v1); acc8(a, v2); acc8(a, v3);
    }
    for (; i < nn; ++i) acc8(a, x[(size_t)lp[i] * 8 + c]);
    int no = lovfc; if (no > OVFB) no = OVFB;
    for (int k2 = 0; k2 < no; ++k2) {
        int e = lovf[k2];
        if ((e >> 17) == lrow) acc8(a, x[(size_t)(e & 0x1FFFF) * 8 + c]);
    }

    float4 blo = *(const float4*)&b2[c * 8];
    float4 bhi = *(const float4*)&b2[c * 8 + 4];
    float4 o0 = make_float4(a[0] + blo.x, a[1] + blo.y, a[2] + blo.z, a[3] + blo.w);
    float4 o1 = make_float4(a[4] + bhi.x, a[5] + bhi.y, a[6] + bhi.z, a[7] + bhi.w);
    out[(size_t)d * 16 + c * 2]     = o0;
    out[(size_t)d * 16 + c * 2 + 1] = o1;
}

extern "C" void kernel_launch(void* const* d_in, const int* in_sizes, int n_in,
                              void* d_out, int out_size, void* d_ws, size_t ws_size,
                              hipStream_t stream) {
    const float* h    = (const float*)d_in[0];
    const float* W1   = (const float*)d_in[1];
    const float* b1   = (const float*)d_in[2];
    const float* W2   = (const float*)d_in[3];
    const float* b2   = (const float*)d_in[4];
    const int*   src0 = (const int*)d_in[5];
    const int*   dst0 = (const int*)d_in[6];
    const int*   src1 = (const int*)d_in[7];
    const int*   dst1 = (const int*)d_in[8];

    const int N0 = in_sizes[0] / 128;    // 100000
    const int E0 = in_sizes[5];          // 600000 (multiple of 8)
    const int E1 = in_sizes[7];          // 120000 (multiple of 8)
    const int ET = E0 + E1;
    const int D0 = D0_CONST;
    const int D1 = D1_CONST;
    const int nbScat = (ET + 4095) / 4096;   // 176

    // Workspace layout (~38 MB), 16B-aligned blocks.
    char* p = (char*)d_ws;
    unsigned short* hbf  = (unsigned short*)p; p += (size_t)N0 * 128 * 2;   // 25.6 MB
    unsigned short* tbf  = (unsigned short*)p; p += (size_t)D0 * 64 * 2;    // 3.2 MB
    unsigned short* W1T  = (unsigned short*)p; p += 128 * 128 * 2;
    unsigned short* W2T  = (unsigned short*)p; p += 64 * 128 * 2;
    unsigned short* gdp  = (unsigned short*)p; p += (size_t)nbScat * 4096 * 2; // padded
    int* rgn      = (int*)p; p += (size_t)NRANGE * RGN_CAP * 4;             // 3.87 MB
    int* rangecur = (int*)p; p += 256 * 4;

    float* out = (float*)d_out;

    // 1) pack gdst + W transpose/cast + range-cursor init (no memsets).
    {
        int n0 = E0 / 8, n1 = E1 / 8;
        int tot = n0 + n1 + 128 * 128 + 128 * 64 + NRANGE;
        prep_pack<<<(tot + 255) / 256, 256, 0, stream>>>(
            dst0, dst1, gdp, W1, W2, W1T, W2T, rangecur, n0, n1);
    }

    // 2) phase-1 multisplit scatter + nt h->bf16 cast (co-scheduled).
    {
        int n8 = N0 * 128 / 8;                       // 1.6M
        int castBlocks = (n8 + 255) / 256;
        scatter_cast<<<nbScat + castBlocks, 256, 0, stream>>>(
            gdp, src0, src1, E0, ET, rgn, rangecur,
            h, (unsigned int*)hbf, n8, nbScat);
    }

    // 3) layer 0 fused: bucket + gather + relu(y0@W1+b1)@W2 -> t.
    {
        int blocks = (D0 + 31) / 32;                 // 782
        gather0_linear<<<blocks, 256, 0, stream>>>(
            (const uint4*)hbf, rgn, rangecur, W1T, W2T, b1, tbf, D0);
    }

    // 4) layer 1 fused: bucket + gather + b2 -> out.
    {
        int blocks = (D1 + 31) / 32;                 // 157
        gather1_kernel<<<blocks, 256, 0, stream>>>(
            (const uint4*)tbf, rgn, rangecur, b2, (float4*)out, D1);
    }
}